// Round 4
// baseline (409.426 us; speedup 1.0000x reference)
//
#include <hip/hip_runtime.h>
#include <math.h>

#define NO_LAYERS 2048
#define MODES 4096
#define APL 8
#define OUT_N (NO_LAYERS * APL)   // 16384

// Re(tanh(t*(Sr+i*Si))), numerically stable for |t*Sr| up to thousands.
// Re tanh(x+iy) = sinh(2x)/(cosh(2x)+cos(2y))
//              = sign(x)*(1-e^{-2a}) / (1+e^{-2a}+2 e^{-a} cos(2y)),  a=2|x|
__device__ __forceinline__ float retanh_cplx(float t, float Sr, float Si) {
    float x = t * Sr;
    float y = t * Si;
    float a = 2.0f * fabsf(x);
    float e1 = expf(-a);          // 0 for a > ~88 (saturated regime)
    float e2 = e1 * e1;
    float num = 1.0f - e2;
    float den = 1.0f + e2 + 2.0f * e1 * cosf(2.0f * y);
    return copysignf(num / den, x);
}

// 8 blocks x 256 threads. Each block redundantly computes the three complex
// sums S0..S2 (96 KB of reads, L2-cached after block 0), then handles 256
// consecutive f values (one strided model_p load per thread).
__global__ void __launch_bounds__(256) k_prep(const float* __restrict__ model_p,
                                              const float* __restrict__ w0,
                                              const float* __restrict__ w1,
                                              const float* __restrict__ w2,
                                              float* __restrict__ t_out) {
    __shared__ float red[3][2][4];
    __shared__ float S[3][2];
    const int tid = threadIdx.x;          // 0..255
    const int wave = tid >> 6, lane = tid & 63;

    const float* wptr[3] = {w0, w1, w2};
    float sr[3] = {0.f, 0.f, 0.f}, si[3] = {0.f, 0.f, 0.f};
    #pragma unroll
    for (int w = 0; w < 3; w++) {
        const float2* p = (const float2*)wptr[w];   // interleaved re,im
        for (int i = tid; i < MODES; i += 256) {
            float2 v = p[i];
            sr[w] += v.x; si[w] += v.y;
        }
    }
    #pragma unroll
    for (int off = 32; off > 0; off >>= 1) {
        #pragma unroll
        for (int w = 0; w < 3; w++) {
            sr[w] += __shfl_down(sr[w], off);
            si[w] += __shfl_down(si[w], off);
        }
    }
    if (lane == 0) {
        #pragma unroll
        for (int w = 0; w < 3; w++) { red[w][0][wave] = sr[w]; red[w][1][wave] = si[w]; }
    }
    __syncthreads();
    if (tid == 0) {
        #pragma unroll
        for (int w = 0; w < 3; w++) {
            S[w][0] = red[w][0][0] + red[w][0][1] + red[w][0][2] + red[w][0][3];
            S[w][1] = red[w][1][0] + red[w][1][1] + red[w][1][2] + red[w][1][3];
        }
    }
    __syncthreads();
    const float S0r = S[0][0], S0i = S[0][1];
    const float S1r = S[1][0], S1i = S[1][1];
    const float S2r = S[2][0], S2i = S[2][1];

    const int f = blockIdx.x * 256 + tid;      // 8 * 256 = 2048
    float t = model_p[(size_t)f * MODES];      // column 0 of model_p
    t = retanh_cplx(t, S0r, S0i);
    t = retanh_cplx(t, S1r, S1i);
    t = retanh_cplx(t, S2r, S2i);
    t_out[f] = t;
}

// h[m] = tanh(dot(t, lin1_w[m,:]) + b[m]);  lin1_w: (4096, 2048) row-major.
// One wave per row; t staged to LDS per block. Plain (cacheable) loads:
// input-restore may leave weights L3-resident — NT hints would bypass that.
__global__ void __launch_bounds__(256) k_lin1(const float* __restrict__ t,
                                              const float* __restrict__ w,
                                              const float* __restrict__ b,
                                              float* __restrict__ h) {
    __shared__ float ts[NO_LAYERS];          // 8 KB
    const int tid = threadIdx.x;
    {
        const float4* tp = (const float4*)t;
        float4* sp = (float4*)ts;
        for (int i = tid; i < NO_LAYERS / 4; i += 256) sp[i] = tp[i];
    }
    __syncthreads();
    const int wave = tid >> 6, lane = tid & 63;
    const int row = blockIdx.x * 4 + wave;   // < 4096
    const float4* wp = (const float4*)(w + (size_t)row * NO_LAYERS);
    const float4* tp = (const float4*)ts;
    float acc = 0.f;
    #pragma unroll
    for (int i = 0; i < (NO_LAYERS / 4) / 64; i++) {   // 8 iters
        int idx = i * 64 + lane;
        float4 wv = wp[idx];
        float4 tv = tp[idx];
        acc += wv.x * tv.x + wv.y * tv.y + wv.z * tv.z + wv.w * tv.w;
    }
    #pragma unroll
    for (int off = 32; off > 0; off >>= 1) acc += __shfl_down(acc, off);
    if (lane == 0) h[row] = tanhf(acc + b[row]);
}

// out[j] = dot(h, lin2_w[j,:]) + b[j];  lin2_w: (16384, 4096) row-major.
// Two rows per wave (32 independent float4 loads in flight), h staged in LDS.
__global__ void __launch_bounds__(256) k_lin2(const float* __restrict__ h,
                                              const float* __restrict__ w,
                                              const float* __restrict__ b,
                                              float* __restrict__ out) {
    __shared__ float hs[MODES];              // 16 KB
    const int tid = threadIdx.x;
    {
        const float4* hp = (const float4*)h;
        float4* sp = (float4*)hs;
        for (int i = tid; i < MODES / 4; i += 256) sp[i] = hp[i];
    }
    __syncthreads();
    const int wave = tid >> 6, lane = tid & 63;
    const int row0 = blockIdx.x * 8 + wave * 2;   // 2048 blocks * 8 rows = 16384
    const float4* wp0 = (const float4*)(w + (size_t)row0 * MODES);
    const float4* wp1 = (const float4*)(w + (size_t)(row0 + 1) * MODES);
    const float4* hp = (const float4*)hs;
    float acc0 = 0.f, acc1 = 0.f;
    #pragma unroll
    for (int i = 0; i < (MODES / 4) / 64; i++) {       // 16 iters
        int idx = i * 64 + lane;
        float4 hv = hp[idx];
        float4 w0v = wp0[idx];
        float4 w1v = wp1[idx];
        acc0 += w0v.x * hv.x + w0v.y * hv.y + w0v.z * hv.z + w0v.w * hv.w;
        acc1 += w1v.x * hv.x + w1v.y * hv.y + w1v.z * hv.z + w1v.w * hv.w;
    }
    #pragma unroll
    for (int off = 32; off > 0; off >>= 1) {
        acc0 += __shfl_down(acc0, off);
        acc1 += __shfl_down(acc1, off);
    }
    if (lane == 0) {
        out[row0]     = acc0 + b[row0];
        out[row0 + 1] = acc1 + b[row0 + 1];
    }
}

extern "C" void kernel_launch(void* const* d_in, const int* in_sizes, int n_in,
                              void* d_out, int out_size, void* d_ws, size_t ws_size,
                              hipStream_t stream) {
    const float* model_p = (const float*)d_in[0];
    const float* w0      = (const float*)d_in[1];   // complex64 interleaved
    const float* w1      = (const float*)d_in[2];
    const float* w2      = (const float*)d_in[3];
    const float* lin1_w  = (const float*)d_in[4];
    const float* lin1_b  = (const float*)d_in[5];
    const float* lin2_w  = (const float*)d_in[6];
    const float* lin2_b  = (const float*)d_in[7];
    float* out = (float*)d_out;

    float* t = (float*)d_ws;          // 2048 floats
    float* h = t + NO_LAYERS;         // 4096 floats

    k_prep<<<8, 256, 0, stream>>>(model_p, w0, w1, w2, t);
    k_lin1<<<1024, 256, 0, stream>>>(t, lin1_w, lin1_b, h);
    k_lin2<<<2048, 256, 0, stream>>>(h, lin2_w, lin2_b, out);
}

// Round 5
// 389.597 us; speedup vs baseline: 1.0509x; 1.0509x over previous
//
#include <hip/hip_runtime.h>
#include <math.h>

#define NO_LAYERS 2048
#define MODES 4096
#define APL 8
#define OUT_N (NO_LAYERS * APL)   // 16384

// Native clang vector type — required by __builtin_nontemporal_load
// (HIP's float4 class is rejected by the builtin's type check).
typedef float nf4 __attribute__((ext_vector_type(4)));

// Re(tanh(t*(Sr+i*Si))), numerically stable for |t*Sr| up to thousands.
// Re tanh(x+iy) = sinh(2x)/(cosh(2x)+cos(2y))
//              = sign(x)*(1-e^{-2a}) / (1+e^{-2a}+2 e^{-a} cos(2y)),  a=2|x|
__device__ __forceinline__ float retanh_cplx(float t, float Sr, float Si) {
    float x = t * Sr;
    float y = t * Si;
    float a = 2.0f * fabsf(x);
    float e1 = expf(-a);          // 0 for a > ~88 (saturated regime)
    float e2 = e1 * e1;
    float num = 1.0f - e2;
    float den = 1.0f + e2 + 2.0f * e1 * cosf(2.0f * y);
    return copysignf(num / den, x);
}

// 8 blocks x 256 threads. Each block redundantly computes the three complex
// sums S0..S2 (96 KB of reads, L2-cached after block 0), then handles 256
// consecutive f values (one strided model_p load per thread).
__global__ void __launch_bounds__(256) k_prep(const float* __restrict__ model_p,
                                              const float* __restrict__ w0,
                                              const float* __restrict__ w1,
                                              const float* __restrict__ w2,
                                              float* __restrict__ t_out) {
    __shared__ float red[3][2][4];
    __shared__ float S[3][2];
    const int tid = threadIdx.x;          // 0..255
    const int wave = tid >> 6, lane = tid & 63;

    const float* wptr[3] = {w0, w1, w2};
    float sr[3] = {0.f, 0.f, 0.f}, si[3] = {0.f, 0.f, 0.f};
    #pragma unroll
    for (int w = 0; w < 3; w++) {
        const float2* p = (const float2*)wptr[w];   // interleaved re,im
        for (int i = tid; i < MODES; i += 256) {
            float2 v = p[i];
            sr[w] += v.x; si[w] += v.y;
        }
    }
    #pragma unroll
    for (int off = 32; off > 0; off >>= 1) {
        #pragma unroll
        for (int w = 0; w < 3; w++) {
            sr[w] += __shfl_down(sr[w], off);
            si[w] += __shfl_down(si[w], off);
        }
    }
    if (lane == 0) {
        #pragma unroll
        for (int w = 0; w < 3; w++) { red[w][0][wave] = sr[w]; red[w][1][wave] = si[w]; }
    }
    __syncthreads();
    if (tid == 0) {
        #pragma unroll
        for (int w = 0; w < 3; w++) {
            S[w][0] = red[w][0][0] + red[w][0][1] + red[w][0][2] + red[w][0][3];
            S[w][1] = red[w][1][0] + red[w][1][1] + red[w][1][2] + red[w][1][3];
        }
    }
    __syncthreads();
    const float S0r = S[0][0], S0i = S[0][1];
    const float S1r = S[1][0], S1i = S[1][1];
    const float S2r = S[2][0], S2i = S[2][1];

    const int f = blockIdx.x * 256 + tid;      // 8 * 256 = 2048
    float t = model_p[(size_t)f * MODES];      // column 0 of model_p
    t = retanh_cplx(t, S0r, S0i);
    t = retanh_cplx(t, S1r, S1i);
    t = retanh_cplx(t, S2r, S2i);
    t_out[f] = t;
}

// h[m] = tanh(dot(t, lin1_w[m,:]) + b[m]);  lin1_w: (4096, 2048) row-major.
// One wave per row; t staged to LDS per block; streaming weights non-temporal
// (read-once 32 MB stream — bypassing L2/L3 avoids cache churn, measured
// R3 vs R4: NT is ~17 us faster per iteration).
__global__ void __launch_bounds__(256) k_lin1(const float* __restrict__ t,
                                              const float* __restrict__ w,
                                              const float* __restrict__ b,
                                              float* __restrict__ h) {
    __shared__ float ts[NO_LAYERS];          // 8 KB
    const int tid = threadIdx.x;
    {
        const float4* tp = (const float4*)t;
        float4* sp = (float4*)ts;
        for (int i = tid; i < NO_LAYERS / 4; i += 256) sp[i] = tp[i];
    }
    __syncthreads();
    const int wave = tid >> 6, lane = tid & 63;
    const int row = blockIdx.x * 4 + wave;   // < 4096
    const nf4* wp = (const nf4*)(w + (size_t)row * NO_LAYERS);
    const float4* tp = (const float4*)ts;
    float acc = 0.f;
    #pragma unroll
    for (int i = 0; i < (NO_LAYERS / 4) / 64; i++) {   // 8 iters
        int idx = i * 64 + lane;
        nf4 wv = __builtin_nontemporal_load(&wp[idx]);
        float4 tv = tp[idx];
        acc += wv.x * tv.x + wv.y * tv.y + wv.z * tv.z + wv.w * tv.w;
    }
    #pragma unroll
    for (int off = 32; off > 0; off >>= 1) acc += __shfl_down(acc, off);
    if (lane == 0) h[row] = tanhf(acc + b[row]);
}

// out[j] = dot(h, lin2_w[j,:]) + b[j];  lin2_w: (16384, 4096) row-major.
// Two rows per wave (32 independent float4 loads in flight), h staged in LDS,
// streaming weights non-temporal (read-once 268 MB stream).
__global__ void __launch_bounds__(256) k_lin2(const float* __restrict__ h,
                                              const float* __restrict__ w,
                                              const float* __restrict__ b,
                                              float* __restrict__ out) {
    __shared__ float hs[MODES];              // 16 KB
    const int tid = threadIdx.x;
    {
        const float4* hp = (const float4*)h;
        float4* sp = (float4*)hs;
        for (int i = tid; i < MODES / 4; i += 256) sp[i] = hp[i];
    }
    __syncthreads();
    const int wave = tid >> 6, lane = tid & 63;
    const int row0 = blockIdx.x * 8 + wave * 2;   // 2048 blocks * 8 rows = 16384
    const nf4* wp0 = (const nf4*)(w + (size_t)row0 * MODES);
    const nf4* wp1 = (const nf4*)(w + (size_t)(row0 + 1) * MODES);
    const float4* hp = (const float4*)hs;
    float acc0 = 0.f, acc1 = 0.f;
    #pragma unroll
    for (int i = 0; i < (MODES / 4) / 64; i++) {       // 16 iters
        int idx = i * 64 + lane;
        float4 hv = hp[idx];
        nf4 w0v = __builtin_nontemporal_load(&wp0[idx]);
        nf4 w1v = __builtin_nontemporal_load(&wp1[idx]);
        acc0 += w0v.x * hv.x + w0v.y * hv.y + w0v.z * hv.z + w0v.w * hv.w;
        acc1 += w1v.x * hv.x + w1v.y * hv.y + w1v.z * hv.z + w1v.w * hv.w;
    }
    #pragma unroll
    for (int off = 32; off > 0; off >>= 1) {
        acc0 += __shfl_down(acc0, off);
        acc1 += __shfl_down(acc1, off);
    }
    if (lane == 0) {
        out[row0]     = acc0 + b[row0];
        out[row0 + 1] = acc1 + b[row0 + 1];
    }
}

extern "C" void kernel_launch(void* const* d_in, const int* in_sizes, int n_in,
                              void* d_out, int out_size, void* d_ws, size_t ws_size,
                              hipStream_t stream) {
    const float* model_p = (const float*)d_in[0];
    const float* w0      = (const float*)d_in[1];   // complex64 interleaved
    const float* w1      = (const float*)d_in[2];
    const float* w2      = (const float*)d_in[3];
    const float* lin1_w  = (const float*)d_in[4];
    const float* lin1_b  = (const float*)d_in[5];
    const float* lin2_w  = (const float*)d_in[6];
    const float* lin2_b  = (const float*)d_in[7];
    float* out = (float*)d_out;

    float* t = (float*)d_ws;          // 2048 floats
    float* h = t + NO_LAYERS;         // 4096 floats

    k_prep<<<8, 256, 0, stream>>>(model_p, w0, w1, w2, t);
    k_lin1<<<1024, 256, 0, stream>>>(t, lin1_w, lin1_b, h);
    k_lin2<<<2048, 256, 0, stream>>>(h, lin2_w, lin2_b, out);
}